// Round 9
// baseline (172.968 us; speedup 1.0000x reference)
//
#include <hip/hip_runtime.h>
#include <hip/hip_bf16.h>
#include <math.h>

// Problem constants (B=8, T=1024, C=768, H=12, D=64)
#define BATCH 8
#define SEQ   1024
#define CH    768
#define NH    12
#define HD    64
#define HSZ   (BATCH * NH * SEQ * HD)   // 6291456 elements = B*T*C

typedef __attribute__((ext_vector_type(8))) short short8;   // 8 bf16 = 4 VGPRs
typedef __attribute__((ext_vector_type(4))) short short4v;
typedef __attribute__((ext_vector_type(4))) float floatx4;  // MFMA C/D frag

// fp32 -> bf16 RNE
static __device__ inline short f2bf(float f) {
    union { float f; unsigned u; } x; x.f = f;
    unsigned r = (x.u + 0x7fffu + ((x.u >> 16) & 1u)) >> 16;
    return (short)r;
}

// async global->LDS, 16B per lane; LDS dest must be wave-uniform base + lane*16
#define GLOAD_LDS16(g, l)                                                     \
    __builtin_amdgcn_global_load_lds(                                         \
        (const __attribute__((address_space(1))) void*)(g),                   \
        (__attribute__((address_space(3))) void*)(l), 16, 0, 0)

// ---------------------------------------------------------------------------
// Prep: weight transpose-casts ONLY. The x fp32->bf16 cast is fused into
// GEMM1's A-staging (saves ~38 MB of pure dtype-conversion traffic).
// ---------------------------------------------------------------------------
#define NTA   ((3 * CH / 32) * (CH / 32))        // 1728 tiles for w_attn
#define NTP   ((CH / 32) * (CH / 32))            // 576 tiles for w_proj

__device__ __forceinline__ void transpose_tile(
    const float* __restrict__ w, short* __restrict__ wt, int K, int N,
    int bx, int by, int tid, float (*tile)[33])
{
    const int tx = tid & 31, ty = tid >> 5;      // 32 x 8
    const int n0 = bx * 32, k0 = by * 32;
    #pragma unroll
    for (int i = 0; i < 4; i++)
        tile[ty + i * 8][tx] = w[(size_t)(k0 + ty + i * 8) * N + n0 + tx];
    __syncthreads();
    #pragma unroll
    for (int i = 0; i < 4; i++)
        wt[(size_t)(n0 + ty + i * 8) * K + k0 + tx] = f2bf(tile[tx][ty + i * 8]);
}

__global__ __launch_bounds__(256) void prep_kernel(
    const float* __restrict__ wa, short* __restrict__ wta,
    const float* __restrict__ wp, short* __restrict__ wtp)
{
    __shared__ float tile[32][33];
    const int bid = blockIdx.x, tid = threadIdx.x;
    if (bid < NTA) {
        transpose_tile(wa, wta, CH, 3 * CH, bid % (3 * CH / 32), bid / (3 * CH / 32), tid, tile);
    } else {
        int t = bid - NTA;
        transpose_tile(wp, wtp, CH, CH, t % (CH / 32), t / (CH / 32), tid, tile);
    }
}

// ---------------------------------------------------------------------------
// bf16 MFMA GEMM (round-0 2-phase structure): C = A @ Bt^T + bias
//  - MODE 1 (GEMM1): A is x in FP32 — reg-staged with inline f2bf cast to the
//    same swizzled LDS slots (B stays global_load_lds). Eliminates the xb
//    intermediate entirely. Epilogue: coalesced q/k/v through LDS.
//  - MODE 0 (GEMM2): A bf16 via global_load_lds (unchanged); fp32 row store.
// ---------------------------------------------------------------------------
template <int MODE, int BM, int BN, int NBLK, int MBX, int WPE>
__global__ __launch_bounds__(256, WPE) void gemm_bt_kernel(
    const void* __restrict__ Av, const short* __restrict__ Bt,
    const float* __restrict__ bias, void* __restrict__ outv,
    int M, int N, int K)
{
    constexpr int MT  = BM / 32;
    constexpr int NT  = BN / 32;
    constexpr int ACH = BM / 64;
    constexpr int BCH = BN / 64;
    constexpr int STAGE_BYTES = (BM + BN) * 128;              // 2 bufs x rows x 64B
    constexpr int EPI_BYTES   = (MODE == 1) ? (BN * 136 * 2) : 0;  // v layout largest
    constexpr int LDS_BYTES   = STAGE_BYTES > EPI_BYTES ? STAGE_BYTES : EPI_BYTES;
    __shared__ __align__(16) char smem[LDS_BYTES];
    short* AsB = (short*)smem;                    // 2 bufs x BM*32
    short* BsB = (short*)(smem + BM * 128);       // 2 bufs x BN*32

    const int tid  = threadIdx.x;
    const int lane = tid & 63;
    const int col  = lane & 15;
    const int quad = lane >> 4;
    const int wave = tid >> 6;
    const int wm = wave & 1, wn = wave >> 1;

    const int bid = blockIdx.x;
    const int j   = bid & 7;
    const int t   = bid >> 3;
    const int mb  = j * MBX + t / NBLK;
    const int nb  = t % NBLK;
    const int m0 = mb * BM, n0 = nb * BN;

    const int srow = tid >> 2;
    const int kc   = ((tid & 3) ^ (srow & 3)) * 8;
    const short* bptr[BCH];
    #pragma unroll
    for (int c = 0; c < BCH; c++)
        bptr[c] = Bt + (size_t)(n0 + c * 64 + srow) * K + kc;

    // A source pointers: fp32 (MODE 1) or bf16 (MODE 0), same swizzled kc
    const float* xptr[ACH];
    const short* aptr[ACH];
    #pragma unroll
    for (int c = 0; c < ACH; c++) {
        if constexpr (MODE == 1)
            xptr[c] = (const float*)Av + (size_t)(m0 + c * 64 + srow) * K + kc;
        else
            aptr[c] = (const short*)Av + (size_t)(m0 + c * 64 + srow) * K + kc;
    }

    floatx4 acc[MT][NT];
    #pragma unroll
    for (int i = 0; i < MT; i++)
        #pragma unroll
        for (int jj = 0; jj < NT; jj++)
            acc[i][jj] = (floatx4){0.f, 0.f, 0.f, 0.f};

    const int niter = K / 32;

    // prologue: stage tile 0
    #pragma unroll
    for (int c = 0; c < BCH; c++) GLOAD_LDS16(bptr[c], &BsB[c * 2048 + tid * 8]);
    if constexpr (MODE == 1) {
        #pragma unroll
        for (int c = 0; c < ACH; c++) {
            float4 f0 = *(const float4*)(xptr[c]);
            float4 f1 = *(const float4*)(xptr[c] + 4);
            short8 s = { f2bf(f0.x), f2bf(f0.y), f2bf(f0.z), f2bf(f0.w),
                         f2bf(f1.x), f2bf(f1.y), f2bf(f1.z), f2bf(f1.w) };
            *(short8*)&AsB[c * 2048 + tid * 8] = s;
        }
    } else {
        #pragma unroll
        for (int c = 0; c < ACH; c++) GLOAD_LDS16(aptr[c], &AsB[c * 2048 + tid * 8]);
    }

    for (int k = 0; k < niter; k++) {
        __syncthreads();
        const int cur = k & 1, nxt = cur ^ 1;
        const bool pf = (k + 1 < niter);
        const int ko = (k + 1) * 32;

        // issue next-tile B DMA + next-tile A global loads early
        float4 f0[ACH], f1[ACH];
        if (pf) {
            #pragma unroll
            for (int c = 0; c < BCH; c++)
                GLOAD_LDS16(bptr[c] + ko, &BsB[nxt * BN * 32 + c * 2048 + tid * 8]);
            if constexpr (MODE == 1) {
                #pragma unroll
                for (int c = 0; c < ACH; c++) {
                    f0[c] = *(const float4*)(xptr[c] + ko);
                    f1[c] = *(const float4*)(xptr[c] + ko + 4);
                }
            } else {
                #pragma unroll
                for (int c = 0; c < ACH; c++)
                    GLOAD_LDS16(aptr[c] + ko, &AsB[nxt * BM * 32 + c * 2048 + tid * 8]);
            }
        }

        short8 af[MT], bf[NT];
        #pragma unroll
        for (int mt = 0; mt < MT; mt++) {
            const int row = wm * (BM / 2) + mt * 16 + col;
            af[mt] = *(const short8*)&AsB[cur * BM * 32 + row * 32 + ((quad ^ (row & 3)) << 3)];
        }
        #pragma unroll
        for (int nt = 0; nt < NT; nt++) {
            const int row = wn * (BN / 2) + nt * 16 + col;
            bf[nt] = *(const short8*)&BsB[cur * BN * 32 + row * 32 + ((quad ^ (row & 3)) << 3)];
        }
        #pragma unroll
        for (int mt = 0; mt < MT; mt++)
            #pragma unroll
            for (int nt = 0; nt < NT; nt++)
                acc[mt][nt] = __builtin_amdgcn_mfma_f32_16x16x32_bf16(
                    af[mt], bf[nt], acc[mt][nt], 0, 0, 0);

        // convert + LDS-write next A tile in the MFMA shadow
        if constexpr (MODE == 1) {
            if (pf) {
                #pragma unroll
                for (int c = 0; c < ACH; c++) {
                    short8 s = { f2bf(f0[c].x), f2bf(f0[c].y), f2bf(f0[c].z), f2bf(f0[c].w),
                                 f2bf(f1[c].x), f2bf(f1[c].y), f2bf(f1[c].z), f2bf(f1[c].w) };
                    *(short8*)&AsB[nxt * BM * 32 + c * 2048 + tid * 8] = s;
                }
            }
        }
    }

    if constexpr (MODE == 0) {
        // fp32 row-major store (already reasonably coalesced)
        #pragma unroll
        for (int mt = 0; mt < MT; mt++) {
            #pragma unroll
            for (int r = 0; r < 4; r++) {
                const int m = m0 + wm * (BM / 2) + mt * 16 + quad * 4 + r;
                #pragma unroll
                for (int nt = 0; nt < NT; nt++) {
                    const int n = n0 + wn * (BN / 2) + nt * 16 + col;
                    ((float*)outv)[(size_t)m * N + n] = acc[mt][nt][r] + bias[n];
                }
            }
        }
    } else {
        // coalesced q/k/v epilogue through LDS
        __syncthreads();                      // staging LDS now reusable
        short* Es = (short*)smem;
        const int sel = n0 / CH;              // uniform per block (192 | 768)
        const int h0  = (n0 - sel * CH) >> 6; // first head of this 3-head slice
        const int bb  = m0 >> 10;
        const int t0  = m0 & 1023;
        short* qkv = (short*)outv;

        if (sel < 2) {
            // LDS [m][n], stride 200 (conflict-broken)
            #pragma unroll
            for (int mt = 0; mt < MT; mt++)
                #pragma unroll
                for (int r = 0; r < 4; r++) {
                    const int lm = wm * (BM / 2) + mt * 16 + quad * 4 + r;
                    #pragma unroll
                    for (int nt = 0; nt < NT; nt++) {
                        const int ln = wn * (BN / 2) + nt * 16 + col;
                        Es[lm * 200 + ln] = f2bf(acc[mt][nt][r] + bias[n0 + ln]);
                    }
                }
            __syncthreads();
            // store: 8 lanes cover one 128B t-row; contiguous across lanes
            #pragma unroll
            for (int it = 0; it < (BM * BN / 8) / 256; it++) {
                const int id = it * 256 + tid;
                const int hp = id >> 10, lm = (id >> 3) & 127, dc = id & 7;
                short8 v = *(const short8*)&Es[lm * 200 + hp * 64 + dc * 8];
                size_t dst = (size_t)sel * HSZ +
                    (((size_t)(bb * NH + h0 + hp)) * SEQ + t0 + lm) * HD + dc * 8;
                *(short8*)&qkv[dst] = v;
            }
        } else {
            // v: LDS [n][m], stride 136; b64 packed writes (r-values m-adjacent)
            #pragma unroll
            for (int nt = 0; nt < NT; nt++) {
                const int ln = wn * (BN / 2) + nt * 16 + col;
                const float bv = bias[n0 + ln];
                #pragma unroll
                for (int mt = 0; mt < MT; mt++) {
                    const int lm = wm * (BM / 2) + mt * 16 + quad * 4;
                    short4v pk;
                    #pragma unroll
                    for (int r = 0; r < 4; r++) pk[r] = f2bf(acc[mt][nt][r] + bv);
                    *(short4v*)&Es[ln * 136 + lm] = pk;
                }
            }
            __syncthreads();
            // store: 16 lanes cover 128 consecutive t per (h,d) row
            #pragma unroll
            for (int it = 0; it < (BM * BN / 8) / 256; it++) {
                const int id = it * 256 + tid;
                const int ln = id >> 4, tc = id & 15;
                short8 v = *(const short8*)&Es[ln * 136 + tc * 8];
                const int hp = ln >> 6, d = ln & 63;
                size_t dst = (size_t)2 * HSZ +
                    (((size_t)(bb * NH + h0 + hp)) * HD + d) * SEQ + t0 + tc * 8;
                *(short8*)&qkv[dst] = v;
            }
        }
    }
}

// ---------------------------------------------------------------------------
// bf16 MFMA flash attention (round-7 structure, kept):
//  - 8 waves x 1 strip, 16 waves/CU, LDS-identical Psh.
//  - 1-D grid, bid = qt*96 + bh: same-bh q-tiles co-locate on one XCD;
//    per-XCD K/V footprint 3 MB < 4 MB L2 (T1 regime).
//  - Causal edge wave-uniform (waves 0-3 diag at kt==2qt, 4-7 at 2qt+1).
// ---------------------------------------------------------------------------
#define LDK 72   // padded row length (bf16) -> 144 B stride

template <bool DIAG>
__device__ __forceinline__ void strip_step(
    const short* __restrict__ Ksh, const short* __restrict__ Vsh,
    short* __restrict__ pw, const short8* aq, floatx4* acc_o,
    floatx4& lacc, short8 bones, int col, int quad, int qrow0)
{
    floatx4 sacc[4];
    #pragma unroll
    for (int i = 0; i < 4; i++) sacc[i] = (floatx4){0.f, 0.f, 0.f, 0.f};
    #pragma unroll
    for (int s = 0; s < 2; s++)
        #pragma unroll
        for (int nt = 0; nt < 4; nt++) {
            short8 bk = *(const short8*)&Ksh[(nt * 16 + col) * LDK + s * 32 + quad * 8];
            sacc[nt] = __builtin_amdgcn_mfma_f32_16x16x32_bf16(aq[s], bk, sacc[nt], 0, 0, 0);
        }

    const float SCL = 0.18033688011112042f;   // 0.125 * log2(e)
    #pragma unroll
    for (int r = 0; r < 4; r++)
        #pragma unroll
        for (int nt = 0; nt < 4; nt++) {
            float sv = sacc[nt][r] * SCL;
            if (DIAG && (nt * 16 + col) > (qrow0 + r)) sv = -INFINITY;
            float pv = __builtin_amdgcn_exp2f(sv);
            pw[(quad * 4 + r) * LDK + nt * 16 + col] =
                (short)(__builtin_bit_cast(unsigned, pv) >> 16);
        }
    __builtin_amdgcn_wave_barrier();

    short8 ap[2];
    ap[0] = *(const short8*)&pw[col * LDK + quad * 8];
    ap[1] = *(const short8*)&pw[col * LDK + 32 + quad * 8];

    #pragma unroll
    for (int s = 0; s < 2; s++) {
        #pragma unroll
        for (int nt = 0; nt < 4; nt++) {
            short8 bv = *(const short8*)&Vsh[(nt * 16 + col) * LDK + s * 32 + quad * 8];
            acc_o[nt] = __builtin_amdgcn_mfma_f32_16x16x32_bf16(ap[s], bv, acc_o[nt], 0, 0, 0);
        }
        lacc = __builtin_amdgcn_mfma_f32_16x16x32_bf16(ap[s], bones, lacc, 0, 0, 0);
    }
}

__global__ __launch_bounds__(512, 4) void attn_kernel(
    const short* __restrict__ Qg, const short* __restrict__ Kg,
    const short* __restrict__ Vg, short* __restrict__ Y)
{
    __shared__ __align__(16) short Ksh[64 * LDK];
    __shared__ __align__(16) short Vsh[64 * LDK];     // [dim][key]
    __shared__ __align__(16) short Psh[8][16 * LDK];  // per-wave strip

    const int tid  = threadIdx.x;
    const int wave = tid >> 6;               // 0..7, one 16-row strip each
    const int lane = tid & 63;
    const int col  = lane & 15;
    const int quad = lane >> 4;
    const int bid = blockIdx.x;              // 0..767
    const int bh  = bid % 96;                // XCD = bh & 7 for ALL q-tiles of bh
    const int qt  = bid / 96;                // 128-row q-tile
    const int b = bh / NH, h = bh - b * NH;

    const size_t kqbase = (size_t)bh * SEQ * HD;   // q,k: [bh][t][d]
    const size_t vbase  = (size_t)bh * HD * SEQ;   // v:   [bh][d][t]

    short8 aq[2];
    {
        const short* qp = Qg + kqbase +
            (size_t)(qt * 128 + wave * 16 + col) * HD + quad * 8;
        aq[0] = *(const short8*)(qp);
        aq[1] = *(const short8*)(qp + 32);
    }

    floatx4 acc_o[4];
    floatx4 lacc = (floatx4){0.f, 0.f, 0.f, 0.f};
    #pragma unroll
    for (int i = 0; i < 4; i++) acc_o[i] = (floatx4){0.f, 0.f, 0.f, 0.f};

    const short one_bf = (short)0x3F80;
    short8 bones = (col == 0)
        ? (short8){one_bf, one_bf, one_bf, one_bf, one_bf, one_bf, one_bf, one_bf}
        : (short8){0, 0, 0, 0, 0, 0, 0, 0};

    const int qrow0 = (wave & 3) * 16 + quad * 4;   // row within 64-row diag tile

    const int idx = tid * 8;                 // 512 lanes x 8 shorts = full tile
    const int row = idx >> 6, offs = idx & 63;

    short8 kreg, vreg;
    {
        const short* ksrc = Kg + kqbase;
        const short* vsrc = Vg + vbase;
        kreg = *(const short8*)&ksrc[idx];
        vreg = *(const short8*)&vsrc[(size_t)row * SEQ + offs];
    }

    const int nkt = 2 * qt + 2;
    for (int kt = 0; kt < nkt; kt++) {
        __syncthreads();
        *(short8*)&Ksh[row * LDK + offs] = kreg;
        *(short8*)&Vsh[row * LDK + offs] = vreg;
        __syncthreads();

        if (kt + 1 < nkt) {
            const short* ksrc = Kg + kqbase + (size_t)(kt + 1) * 64 * HD;
            const short* vsrc = Vg + vbase + (kt + 1) * 64;
            kreg = *(const short8*)&ksrc[idx];
            vreg = *(const short8*)&vsrc[(size_t)row * SEQ + offs];
        }

        if (kt < 2 * qt) {
            strip_step<false>(Ksh, Vsh, Psh[wave], aq, acc_o, lacc,
                              bones, col, quad, qrow0);
        } else if (kt == 2 * qt) {
            if (wave < 4)
                strip_step<true>(Ksh, Vsh, Psh[wave], aq, acc_o, lacc,
                                 bones, col, quad, qrow0);
            else
                strip_step<false>(Ksh, Vsh, Psh[wave], aq, acc_o, lacc,
                                  bones, col, quad, qrow0);
        } else {
            if (wave >= 4)
                strip_step<true>(Ksh, Vsh, Psh[wave], aq, acc_o, lacc,
                                 bones, col, quad, qrow0);
            // waves 0-3 idle on the final half-tile
        }
    }

    #pragma unroll
    for (int r = 0; r < 4; r++) {
        float l = __shfl(lacc[r], quad * 16, 64);
        float inv = 1.f / l;
        int t = qt * 128 + wave * 16 + quad * 4 + r;
        size_t ybase = ((size_t)(b * SEQ + t)) * CH + h * HD;
        #pragma unroll
        for (int nt = 0; nt < 4; nt++)
            Y[ybase + nt * 16 + col] = f2bf(acc_o[nt][r] * inv);
    }
}

// ---------------------------------------------------------------------------
extern "C" void kernel_launch(void* const* d_in, const int* in_sizes, int n_in,
                              void* d_out, int out_size, void* d_ws, size_t ws_size,
                              hipStream_t stream)
{
    const float* x      = (const float*)d_in[0];  // [B,T,C]
    const float* w_attn = (const float*)d_in[1];  // [C,3C]
    const float* b_attn = (const float*)d_in[2];  // [3C]
    const float* w_proj = (const float*)d_in[3];  // [C,C]
    const float* b_proj = (const float*)d_in[4];  // [C]
    float* out = (float*)d_out;                   // [B,T,C] fp32

    // workspace layout (bf16 shorts)
    short* qkv16 = (short*)d_ws;                          // 3*HSZ
    short* y16   = qkv16 + (size_t)3 * HSZ;               // HSZ   [B,T,C]
    short* wta   = y16   + (size_t)HSZ;                   // [3C, C] = w_attn^T
    short* wtp   = wta   + (size_t)3 * CH * CH;           // [C, C]  = w_proj^T

    const int M = BATCH * SEQ;   // 8192

    // Prep: transpose-cast both weights (x-cast now fused into GEMM1)
    prep_kernel<<<NTA + NTP, 256, 0, stream>>>(w_attn, wta, w_proj, wtp);

    // GEMM1: qkv = x @ w_attn + b_attn -> bf16 q/k/v (v transposed)
    // A = x fp32, reg-staged + inline cast. 128x192 tiles, 3 blocks/CU.
    gemm_bt_kernel<1, 128, 192, 12, 8, 3><<<768, 256, 0, stream>>>(
        x, wta, b_attn, qkv16, M, 3 * CH, CH);

    // Flash attention -> y16 bf16 [B,T,C]; 8-wave strips, L2-local 1-D grid
    attn_kernel<<<768, 512, 0, stream>>>(qkv16, qkv16 + (size_t)HSZ,
                                         qkv16 + (size_t)2 * HSZ, y16);

    // GEMM2: out = y @ w_proj + b_proj (fp32 out)
    // 64x192 tiles, grid = 8 xcd * 16 m * 4 n = 512 = 2 blocks/CU
    gemm_bt_kernel<0, 64, 192, 4, 16, 4><<<512, 256, 0, stream>>>(
        y16, wtp, b_proj, out, M, CH, CH);
}